// Round 1
// 204.278 us; speedup vs baseline: 1.1276x; 1.1276x over previous
//
#include <hip/hip_runtime.h>
#include <math.h>

#define NHEAD  16
#define DHEAD  64
#define DLAT   32
#define TSEQ   2048
#define NBATCH 2
#define CDIM   1024
#define MROWS  (NBATCH*TSEQ)   // 4096

typedef __attribute__((ext_vector_type(8))) short bf16x8;
typedef __attribute__((ext_vector_type(4))) float f32x4;

#define AS1 __attribute__((address_space(1)))
#define AS3 __attribute__((address_space(3)))

__device__ __forceinline__ unsigned short f2bf(float f) {
    union { float f; unsigned u; } v; v.f = f;
    unsigned r = v.u + 0x7fff + ((v.u >> 16) & 1);   // RNE
    return (unsigned short)(r >> 16);
}

// pack two floats -> bf16 pair (RNE), lo | hi<<16
__device__ __forceinline__ unsigned pk2(float lo, float hi) {
    return (unsigned)f2bf(lo) | ((unsigned)f2bf(hi) << 16);
}

// pack bf16(lo)|bf16(hi)<<16 by truncation — one v_perm_b32
__device__ __forceinline__ unsigned pack_trunc(float hi, float lo) {
    return __builtin_amdgcn_perm(__float_as_uint(hi), __float_as_uint(lo), 0x07060302u);
}

__device__ __forceinline__ void gld_lds16(const unsigned short* g, unsigned short* l) {
    __builtin_amdgcn_global_load_lds((const AS1 void*)g, (AS3 void*)l, 16, 0, 0);
}

// ---------------- fp32 -> bf16: x and all six weights in ONE launch ----------------
__global__ __launch_bounds__(256) void cvt_all(
        const float* __restrict__ x,  const float* __restrict__ wq,
        const float* __restrict__ wk, const float* __restrict__ wv,
        const float* __restrict__ wc, const float* __restrict__ wku,
        const float* __restrict__ wvu,
        unsigned short* __restrict__ xb, unsigned short* __restrict__ wall) {
    int i = (blockIdx.x * 256 + threadIdx.x) * 4;
    const float* src; unsigned short* dst; int off;
    if      (i < 4194304) { src = x;   dst = xb;             off = 0;       }
    else if (i < 5242880) { src = wq;  dst = wall;           off = 4194304; }
    else if (i < 5767168) { src = wk;  dst = wall + 1048576; off = 5242880; }
    else if (i < 6291456) { src = wv;  dst = wall + 1572864; off = 5767168; }
    else if (i < 7340032) { src = wc;  dst = wall + 2097152; off = 6291456; }
    else if (i < 7342080) { src = wku; dst = wall + 3145728; off = 7340032; }
    else                  { src = wvu; dst = wall + 3147776; off = 7342080; }
    float4 v = *(const float4*)(src + (i - off));
    ushort4 o = { f2bf(v.x), f2bf(v.y), f2bf(v.z), f2bf(v.w) };
    *(ushort4*)(dst + (i - off)) = o;
}

// ---------------- MFMA GEMM core: 128x128 tile, BK=32, 4 waves ----------------
__device__ __forceinline__ void gemm_core(
        const unsigned short* __restrict__ A, const unsigned short* __restrict__ W,
        int K, int bm, int bn, unsigned short* As, unsigned short* Bs,
        f32x4 (&acc)[4][4]) {
    const int tid = threadIdx.x;
    const int w = tid >> 6, lane = tid & 63;
    const int quad = lane >> 4, l16 = lane & 15;
    const int wm = (w >> 1) * 64, wn = (w & 1) * 64;

    const int lr = lane >> 2;
    const int le = (lane & 3) * 8;
    const unsigned short* Ag0 = A + (size_t)(bm + w*32 + lr) * K + le;
    const unsigned short* Wg0 = W + (size_t)(bn + w*32 + lr) * K + le;
    unsigned short* AsD0 = &As[(w*32 +  0) * 32];
    unsigned short* AsD1 = &As[(w*32 + 16) * 32];
    unsigned short* BsD0 = &Bs[(w*32 +  0) * 32];
    unsigned short* BsD1 = &Bs[(w*32 + 16) * 32];

    for (int k0 = 0; k0 < K; k0 += 32) {
        gld_lds16(Ag0 + k0,                AsD0);
        gld_lds16(Ag0 + k0 + (size_t)16*K, AsD1);
        gld_lds16(Wg0 + k0,                BsD0);
        gld_lds16(Wg0 + k0 + (size_t)16*K, BsD1);
        __syncthreads();
        bf16x8 af[4], bf[4];
        #pragma unroll
        for (int t = 0; t < 4; ++t)
            af[t] = *(const bf16x8*)&As[(wm + t*16 + l16)*32 + quad*8];
        #pragma unroll
        for (int c = 0; c < 4; ++c)
            bf[c] = *(const bf16x8*)&Bs[(wn + c*16 + l16)*32 + quad*8];
        #pragma unroll
        for (int t = 0; t < 4; ++t)
            #pragma unroll
            for (int c = 0; c < 4; ++c)
                acc[t][c] = __builtin_amdgcn_mfma_f32_16x16x32_bf16(af[t], bf[c], acc[t][c], 0, 0, 0);
        __syncthreads();
    }
}

__global__ __launch_bounds__(256) void gemm_proj(
        const unsigned short* __restrict__ A, const unsigned short* __restrict__ W,
        float* __restrict__ qproj, float* __restrict__ okl, float* __restrict__ ovl,
        int K) {
    __shared__ unsigned short As[128*32];
    __shared__ unsigned short Bs[128*32];
    const int bm = blockIdx.y * 128, bn = blockIdx.x * 128;
    f32x4 acc[4][4] = {};
    gemm_core(A, W, K, bm, bn, As, Bs, acc);

    const int tid = threadIdx.x;
    const int w = tid >> 6, lane = tid & 63;
    const int quad = lane >> 4, l16 = lane & 15;
    const int wm = (w >> 1) * 64, wn = (w & 1) * 64;

    float* base; int ldo;
    if (bn < 1024)      { base = qproj + bn;        ldo = 1024; }
    else if (bn < 1536) { base = okl + (bn - 1024); ldo = 512;  }
    else                { base = ovl + (bn - 1536); ldo = 512;  }

    #pragma unroll
    for (int t = 0; t < 4; ++t)
        #pragma unroll
        for (int c = 0; c < 4; ++c)
            #pragma unroll
            for (int r = 0; r < 4; ++r) {
                int row = bm + wm + t*16 + quad*4 + r;
                int col = wn + c*16 + l16;
                base[(size_t)row * ldo + col] = acc[t][c][r];
            }
}

__global__ __launch_bounds__(256) void gemm_out(
        const unsigned short* __restrict__ A, const unsigned short* __restrict__ W,
        float* __restrict__ O, int N, int K) {
    __shared__ unsigned short As[128*32];
    __shared__ unsigned short Bs[128*32];
    const int bm = blockIdx.y * 128, bn = blockIdx.x * 128;
    f32x4 acc[4][4] = {};
    gemm_core(A, W, K, bm, bn, As, Bs, acc);

    const int tid = threadIdx.x;
    const int w = tid >> 6, lane = tid & 63;
    const int quad = lane >> 4, l16 = lane & 15;
    const int wm = (w >> 1) * 64, wn = (w & 1) * 64;
    #pragma unroll
    for (int t = 0; t < 4; ++t)
        #pragma unroll
        for (int c = 0; c < 4; ++c)
            #pragma unroll
            for (int r = 0; r < 4; ++r) {
                int row = bm + wm + t*16 + quad*4 + r;
                int col = bn + wn + c*16 + l16;
                O[(size_t)row * N + col] = acc[t][c][r];
            }
}

// ---------------- fused latent up-proj (k,v) via MFMA + q load + RoPE ----------------
// R7 (this round): old latup was latency-bound (61 µs, VALUBusy 15%, Occ 19%) —
// 1024 scalar FMAs/thread against global-resident Wku/Wvu + 2 block barriers.
// New structure: one MFMA 16x16x32 per 16dim×16tok tile (K=32 exact). Each wave
// independently owns 16 tokens of one (b,h): zero __syncthreads, per-wave LDS
// slabs for the output transposes. W-frags come from bf16 copies made in cvt_all.
// MFMA D layout: dim = quad*4+r, token = l16 -> RoPE pairs live inside one acc.
__global__ __launch_bounds__(256) void latup(
        const float* __restrict__ qproj, const float* __restrict__ klat,
        const float* __restrict__ vlat,
        const unsigned short* __restrict__ wkub, const unsigned short* __restrict__ wvub,
        unsigned short* __restrict__ qb, unsigned short* __restrict__ kb,
        unsigned short* __restrict__ vt) {
    __shared__ __attribute__((aligned(16))) unsigned short ksh[4][16][72];
    __shared__ __attribute__((aligned(16))) unsigned short qsh[4][16][72];
    __shared__ __attribute__((aligned(16))) unsigned short vsh[4][64][24];

    const int bh = blockIdx.y, b = bh >> 4, h = bh & 15;
    const int tid = threadIdx.x, w = tid >> 6, lane = tid & 63;
    const int quad = lane >> 4, l16 = lane & 15;
    const int tw = blockIdx.x * 64 + w * 16;   // wave's 16-token base
    const int t  = tw + l16;

    // B-frags (latents): row = token(l16), k = quad*8..+7 — 128 B/token across 4 lanes
    const float* klp = klat + ((size_t)(b*TSEQ + t))*(NHEAD*DLAT) + h*DLAT + quad*8;
    const float* vlp = vlat + ((size_t)(b*TSEQ + t))*(NHEAD*DLAT) + h*DLAT + quad*8;
    float4 kA = *(const float4*)klp, kB = *(const float4*)(klp + 4);
    float4 vA = *(const float4*)vlp, vB = *(const float4*)(vlp + 4);

    // A-frags (Wku/Wvu bf16): row = dim(c*16+l16), k = quad*8..+7
    bf16x8 xk[4], xv[4];
    #pragma unroll
    for (int c = 0; c < 4; ++c) {
        xk[c] = *(const bf16x8*)&wkub[(c*16 + l16)*DLAT + quad*8];
        xv[c] = *(const bf16x8*)&wvub[(c*16 + l16)*DLAT + quad*8];
    }

    union { bf16x8 v; unsigned u[4]; } yk, yv;
    yk.u[0] = pk2(kA.x, kA.y); yk.u[1] = pk2(kA.z, kA.w);
    yk.u[2] = pk2(kB.x, kB.y); yk.u[3] = pk2(kB.z, kB.w);
    yv.u[0] = pk2(vA.x, vA.y); yv.u[1] = pk2(vA.z, vA.w);
    yv.u[2] = pk2(vB.x, vB.y); yv.u[3] = pk2(vB.z, vB.w);

    f32x4 aK[4], aV[4];
    #pragma unroll
    for (int c = 0; c < 4; ++c) {
        f32x4 z = {0.f, 0.f, 0.f, 0.f};
        aK[c] = __builtin_amdgcn_mfma_f32_16x16x32_bf16(xk[c], yk.v, z, 0, 0, 0);
        aV[c] = __builtin_amdgcn_mfma_f32_16x16x32_bf16(xv[c], yv.v, z, 0, 0, 0);
    }

    // angles: dim d = (c&1)*16 + quad*4 + j, freq idx = d&31 — only 8 distinct/thread
    float C0[4], S0[4], C1[4], S1[4];
    const float tf = (float)t;
    #pragma unroll
    for (int j = 0; j < 4; ++j) {
        float f0 = (float)(quad*4 + j);
        __sincosf(tf * __expf(-f0 * 0.28782313662425572f),          &S0[j], &C0[j]);
        __sincosf(tf * __expf(-(f0 + 16.f) * 0.28782313662425572f), &S1[j], &C1[j]);
    }

    const float* qrow = qproj + ((size_t)(b*TSEQ + t))*CDIM + h*DHEAD;
    #pragma unroll
    for (int c = 0; c < 4; ++c) {
        const float* Cs = (c & 1) ? C1 : C0;
        const float* Ss = (c & 1) ? S1 : S0;
        float a0 = aK[c][0], a1 = aK[c][1], a2 = aK[c][2], a3 = aK[c][3];
        unsigned kw0 = pk2(a0*Cs[0] - a1*Ss[0], a1*Cs[1] + a0*Ss[1]);
        unsigned kw1 = pk2(a2*Cs[2] - a3*Ss[2], a3*Cs[3] + a2*Ss[3]);
        *(uint2*)&ksh[w][l16][c*16 + quad*4] = make_uint2(kw0, kw1);

        float4 qv = *(const float4*)(qrow + c*16 + quad*4);
        unsigned qw0 = pk2((qv.x*Cs[0] - qv.y*Ss[0])*0.125f, (qv.y*Cs[1] + qv.x*Ss[1])*0.125f);
        unsigned qw1 = pk2((qv.z*Cs[2] - qv.w*Ss[2])*0.125f, (qv.w*Cs[3] + qv.z*Ss[3])*0.125f);
        *(uint2*)&qsh[w][l16][c*16 + quad*4] = make_uint2(qw0, qw1);

        vsh[w][c*16 + quad*4 + 0][l16] = f2bf(aV[c][0]);
        vsh[w][c*16 + quad*4 + 1][l16] = f2bf(aV[c][1]);
        vsh[w][c*16 + quad*4 + 2][l16] = f2bf(aV[c][2]);
        vsh[w][c*16 + quad*4 + 3][l16] = f2bf(aV[c][3]);
    }

    // wave-local transpose: lockstep + drain LDS writes (no __syncthreads needed)
    __asm__ __volatile__("s_waitcnt lgkmcnt(0)" ::: "memory");

    const int ro = lane >> 2, co = (lane & 3) * 16;
    size_t go = ((size_t)bh*TSEQ + tw + ro)*DHEAD + co;
    int4 k0o = *(const int4*)&ksh[w][ro][co];
    int4 k1o = *(const int4*)&ksh[w][ro][co + 8];
    *(int4*)&kb[go]     = k0o;
    *(int4*)&kb[go + 8] = k1o;
    int4 q0o = *(const int4*)&qsh[w][ro][co];
    int4 q1o = *(const int4*)&qsh[w][ro][co + 8];
    *(int4*)&qb[go]     = q0o;
    *(int4*)&qb[go + 8] = q1o;

    size_t vo = ((size_t)bh*DHEAD + lane)*TSEQ + tw;
    int4 v0o = *(const int4*)&vsh[w][lane][0];
    int4 v1o = *(const int4*)&vsh[w][lane][8];
    *(int4*)&vt[vo]     = v0o;
    *(int4*)&vt[vo + 8] = v1o;
}

// ---------------- Flash attention: gld_lds DMA staging, XOR-swizzled LDS, no spills ----------------
// R6 post-mortem: 193 MB/dispatch of scratch spill writes (kreg/vreg prefetch state).
// Fix: K/V staged by global_load_lds (zero register footprint). gld_lds forces
// dest = wave-uniform base + lane*16 (no padding), so tiles are unpadded with an
// XOR bank swizzle applied on the per-lane *source* address:
//   K  [128][64]: phys col16 = log col16 ^ (row & 7)
//   V^T[64][128]: phys col16 = log col16 ^ (row & 15)
__global__ __launch_bounds__(256, 2) void flash_attn(
        const unsigned short* __restrict__ qb, const unsigned short* __restrict__ kb,
        const unsigned short* __restrict__ vtb, unsigned short* __restrict__ yatt) {
    const int bh = blockIdx.x;
    const int b = bh >> 4, h = bh & 15;

    __shared__ unsigned short Ks[2][128][64];    // 32 KB
    __shared__ unsigned short VTs[2][64][128];   // 32 KB

    const int tid  = threadIdx.x;
    const int wq   = tid >> 6;
    const int lane = tid & 63;
    const int quad = lane >> 4;
    const int l16  = lane & 15;

    const unsigned short* Kbase = kb  + (size_t)bh * TSEQ * DHEAD;
    const unsigned short* Vbase = vtb + (size_t)bh * DHEAD * TSEQ;

    // DMA source lane-mapping (swizzled)
    const int kr8 = lane >> 3, kcp = lane & 7;
    const int kcl = (kcp ^ kr8) * 8;              // K logical elem offset in row
    const int vr4 = lane >> 4, vcp = lane & 15;

    // swizzled MFMA read offsets
    const int kx0 = (quad ^ (l16 & 7)) * 8;
    const int kx1 = ((quad + 4) ^ (l16 & 7)) * 8;

    const int idx01 = (((lane >> 4) & 1) * 32 + l16) * 4;
    const int idx23 = idx01 + 64;
    const bool hi = (lane & 32) != 0;

    for (int half = 0; half < 2; ++half) {
        const int qt = half ? (31 - (int)blockIdx.y) : (int)blockIdx.y;
        const int n128 = (qt + 2) >> 1;

        const unsigned short* qbase =
            qb + ((size_t)bh*TSEQ + qt*64 + wq*16 + l16) * DHEAD + quad*8;
        bf16x8 qB0 = *(const bf16x8*)qbase;
        bf16x8 qB1 = *(const bf16x8*)(qbase + 32);

        f32x4 oacc[4] = {};
        float m_run = -1e30f, l_run = 0.f;

        __syncthreads();   // prev half's epilogue LDS reads done before DMA overwrites
        #pragma unroll
        for (int i = 0; i < 4; ++i) {   // preload tile 0 into buf 0
            gld_lds16(Kbase + (size_t)(wq*32 + i*8 + kr8)*DHEAD + kcl,
                      &Ks[0][wq*32 + i*8][0]);
            int vcl = (vcp ^ ((i*4 + vr4) & 15)) * 8;
            gld_lds16(Vbase + (size_t)(wq*16 + i*4 + vr4)*TSEQ + vcl,
                      &VTs[0][wq*16 + i*4][0]);
        }
        __syncthreads();

        for (int j = 0; j < n128; ++j) {
            const int buf = j & 1;
            if (j + 1 < n128) {   // async DMA prefetch of next tile into buf^1
                const int kc = (j + 1) * 128;
                #pragma unroll
                for (int i = 0; i < 4; ++i) {
                    gld_lds16(Kbase + (size_t)(kc + wq*32 + i*8 + kr8)*DHEAD + kcl,
                              &Ks[buf^1][wq*32 + i*8][0]);
                    int vcl = (vcp ^ ((i*4 + vr4) & 15)) * 8;
                    gld_lds16(Vbase + (size_t)(wq*16 + i*4 + vr4)*TSEQ + kc + vcl,
                              &VTs[buf^1][wq*16 + i*4][0]);
                }
            }

            // S^T = K Q^T  (8 chunks of 16 K-rows)
            f32x4 sacc[8];
            #pragma unroll
            for (int c = 0; c < 8; ++c) {
                bf16x8 ak0 = *(const bf16x8*)&Ks[buf][c*16 + l16][kx0];
                bf16x8 ak1 = *(const bf16x8*)&Ks[buf][c*16 + l16][kx1];
                f32x4 z = {0.f, 0.f, 0.f, 0.f};
                z = __builtin_amdgcn_mfma_f32_16x16x32_bf16(ak0, qB0, z, 0, 0, 0);
                z = __builtin_amdgcn_mfma_f32_16x16x32_bf16(ak1, qB1, z, 0, 0, 0);
                sacc[c] = z;
            }
            if (j == n128 - 1) {   // causal mask (covers the 128-overhang too)
                #pragma unroll
                for (int c = 0; c < 8; ++c)
                    #pragma unroll
                    for (int r = 0; r < 4; ++r)
                        if (j*128 + c*16 + quad*4 + r > qt*64 + wq*16 + l16)
                            sacc[c][r] = -1e30f;
            }

            // online softmax (per-lane scalar stats, 2-step cross-quad reduce)
            float mx = -1e30f;
            #pragma unroll
            for (int c = 0; c < 8; ++c)
                #pragma unroll
                for (int r = 0; r < 4; ++r) mx = fmaxf(mx, sacc[c][r]);
            mx = fmaxf(mx, __shfl_xor(mx, 16, 64));
            mx = fmaxf(mx, __shfl_xor(mx, 32, 64));
            float mn = fmaxf(m_run, mx);
            float alpha = __expf(m_run - mn);
            m_run = mn;
            float ls = 0.f;
            #pragma unroll
            for (int c = 0; c < 8; ++c)
                #pragma unroll
                for (int r = 0; r < 4; ++r) {
                    float p = __expf(sacc[c][r] - mn);
                    sacc[c][r] = p;
                    ls += p;
                }
            ls += __shfl_xor(ls, 16, 64);
            ls += __shfl_xor(ls, 32, 64);
            l_run = l_run * alpha + ls;
            #pragma unroll
            for (int c = 0; c < 4; ++c)
                #pragma unroll
                for (int r = 0; r < 4; ++r) oacc[c][r] *= alpha;

            // per-g: pack 2 P-chunks -> bpermute to B-frag -> 4 PV MFMAs
            #pragma unroll
            for (int g = 0; g < 4; ++g) {
                unsigned p0a = pack_trunc(sacc[2*g][1],   sacc[2*g][0]);
                unsigned p0b = pack_trunc(sacc[2*g][3],   sacc[2*g][2]);
                unsigned p1a = pack_trunc(sacc[2*g+1][1], sacc[2*g+1][0]);
                unsigned p1b = pack_trunc(sacc[2*g+1][3], sacc[2*g+1][2]);
                union { bf16x8 v; int d[4]; } bP;
                int a0 = __builtin_amdgcn_ds_bpermute(idx01, (int)p0a);
                int b0 = __builtin_amdgcn_ds_bpermute(idx01, (int)p1a);
                bP.d[0] = hi ? b0 : a0;
                int a1 = __builtin_amdgcn_ds_bpermute(idx01, (int)p0b);
                int b1 = __builtin_amdgcn_ds_bpermute(idx01, (int)p1b);
                bP.d[1] = hi ? b1 : a1;
                int a2 = __builtin_amdgcn_ds_bpermute(idx23, (int)p0a);
                int b2 = __builtin_amdgcn_ds_bpermute(idx23, (int)p1a);
                bP.d[2] = hi ? b2 : a2;
                int a3 = __builtin_amdgcn_ds_bpermute(idx23, (int)p0b);
                int b3 = __builtin_amdgcn_ds_bpermute(idx23, (int)p1b);
                bP.d[3] = hi ? b3 : a3;
                #pragma unroll
                for (int c = 0; c < 4; ++c) {
                    bf16x8 av = *(const bf16x8*)&VTs[buf][c*16 + l16][((g*4 + quad) ^ l16) * 8];
                    oacc[c] = __builtin_amdgcn_mfma_f32_16x16x32_bf16(av, bP.v, oacc[c], 0, 0, 0);
                }
            }

            __syncthreads();   // drains prefetch DMA + protects buf reuse
        }

        // epilogue: O^T -> O via per-wave LDS scratch (stride 72), coalesced 16B stores
        float invl = 1.0f / l_run;
        unsigned short* Wt = &Ks[0][0][0] + wq * (16*72);
        #pragma unroll
        for (int c = 0; c < 4; ++c)
            #pragma unroll
            for (int r = 0; r < 4; ++r)
                Wt[(size_t)l16*72 + c*16 + quad*4 + r] = f2bf(oacc[c][r] * invl);
        __asm__ __volatile__("" ::: "memory");
        #pragma unroll
        for (int p = 0; p < 2; ++p) {
            int row = p*8 + (lane >> 3);
            int d0 = (lane & 7) * 8;
            int4 val = *(const int4*)&Wt[row*72 + d0];
            int tg = qt*64 + wq*16 + row;
            *(int4*)&yatt[((size_t)(b*TSEQ + tg))*CDIM + h*DHEAD + d0] = val;
        }
    }
}

extern "C" void kernel_launch(void* const* d_in, const int* in_sizes, int n_in,
                              void* d_out, int out_size, void* d_ws, size_t ws_size,
                              hipStream_t stream) {
    const float* x   = (const float*)d_in[0];
    const float* Wq  = (const float*)d_in[1];
    const float* Wk  = (const float*)d_in[2];
    const float* Wv  = (const float*)d_in[3];
    const float* Wku = (const float*)d_in[4];
    const float* Wvu = (const float*)d_in[5];
    const float* Wc  = (const float*)d_in[6];

    float* out_y  = (float*)d_out;
    float* out_kl = out_y  + (size_t)MROWS * CDIM;
    float* out_vl = out_kl + (size_t)MROWS * NHEAD*DLAT;

    float* qproj = (float*)d_ws;                                           // 16 MB fp32
    unsigned short* xb   = (unsigned short*)(qproj + (size_t)MROWS*CDIM);  // 8 MB
    unsigned short* qb   = xb  + (size_t)MROWS*CDIM;                       // 8 MB
    unsigned short* kb   = qb  + (size_t)MROWS*CDIM;                       // 8 MB
    unsigned short* vt   = kb  + (size_t)MROWS*CDIM;                       // 8 MB
    unsigned short* wall = vt  + (size_t)MROWS*CDIM;                       // [Wq;Wk;Wv;Wc;Wku;Wvu]
    unsigned short* wcb  = wall + (size_t)2048*CDIM;
    unsigned short* wkub = wall + 3145728;
    unsigned short* wvub = wall + 3147776;
    unsigned short* yatt = (unsigned short*)qproj;   // alias: qproj dead after latup

    cvt_all<<<7172, 256, 0, stream>>>(x, Wq, Wk, Wv, Wc, Wku, Wvu, xb, wall);

    gemm_proj<<<dim3(2048/128, MROWS/128), 256, 0, stream>>>(
        xb, wall, qproj, out_kl, out_vl, CDIM);

    latup<<<dim3(TSEQ/64, NBATCH*NHEAD), 256, 0, stream>>>(
        qproj, out_kl, out_vl, wkub, wvub, qb, kb, vt);

    flash_attn<<<dim3(NBATCH*NHEAD, 16), 256, 0, stream>>>(qb, kb, vt, yatt);

    gemm_out<<<dim3(CDIM/128, MROWS/128), 256, 0, stream>>>(yatt, wcb, out_y, CDIM, CDIM);
}